// Round 14
// baseline (321.622 us; speedup 1.0000x reference)
//
#include <hip/hip_runtime.h>
#include <hip/hip_bf16.h>

#define D_MODEL  1280
#define D_BOTTLE 64
#define LN_EPS   1e-5f
#define TM       8          // rows per block
#define XS       1284       // f32 elems per LDS row: 1280 + 4 pad -> 4-bank shift per row
#define GP       72         // g_lds row stride (bf16 elems)

typedef __attribute__((ext_vector_type(8))) short short8;
typedef __attribute__((ext_vector_type(4))) float floatx4;

static __device__ inline unsigned short f2bf(float f) {
    __hip_bfloat16 h = __float2bfloat16(f);
    return *reinterpret_cast<unsigned short*>(&h);
}
static __device__ inline float bf2f(unsigned short u) {
    unsigned int v = ((unsigned int)u) << 16;
    return __uint_as_float(v);
}
static __device__ inline short8 cvt8(float4 a0, float4 a1) {
    short8 r;
    r[0] = (short)f2bf(a0.x); r[1] = (short)f2bf(a0.y);
    r[2] = (short)f2bf(a0.z); r[3] = (short)f2bf(a0.w);
    r[4] = (short)f2bf(a1.x); r[5] = (short)f2bf(a1.y);
    r[6] = (short)f2bf(a1.z); r[7] = (short)f2bf(a1.w);
    return r;
}

// Prep 1: wg = bf16(wd * gamma) [64][1280] ; wu_b = bf16(wu) [1280][64]
__global__ void prep_weights(const float* __restrict__ wd, const float* __restrict__ gamma,
                             const float* __restrict__ wu,
                             unsigned short* __restrict__ wg, unsigned short* __restrict__ wu_b) {
    int i = blockIdx.x * blockDim.x + threadIdx.x;
    if (i < D_MODEL * D_BOTTLE) {
        int k = i % D_MODEL;
        wg[i]   = f2bf(wd[i] * gamma[k]);
        wu_b[i] = f2bf(wu[i]);
    }
}

// Prep 2: colsum[n] = sum_k bf2f(wg[n,k]) ; bd2[n] = b_down[n] + sum_k wd[n,k]*beta[k]
__global__ void prep_reduce(const unsigned short* __restrict__ wg, const float* __restrict__ wd,
                            const float* __restrict__ beta, const float* __restrict__ b_down,
                            float* __restrict__ colsum, float* __restrict__ bd2) {
    const int n = blockIdx.x;
    const int t = threadIdx.x;
    float cs = 0.f, bb = 0.f;
    for (int k = t; k < D_MODEL; k += 256) {
        cs += bf2f(wg[n * D_MODEL + k]);
        bb += wd[n * D_MODEL + k] * beta[k];
    }
    #pragma unroll
    for (int m = 1; m < 64; m <<= 1) {
        cs += __shfl_xor(cs, m);
        bb += __shfl_xor(bb, m);
    }
    __shared__ float scs[4], sbb[4];
    if ((t & 63) == 0) { scs[t >> 6] = cs; sbb[t >> 6] = bb; }
    __syncthreads();
    if (t == 0) {
        colsum[n] = scs[0] + scs[1] + scs[2] + scs[3];
        bd2[n]    = b_down[n] + sbb[0] + sbb[1] + sbb[2] + sbb[3];
    }
}

__global__ __launch_bounds__(256, 3) void adapter_kernel(
    const float* __restrict__ x,
    const unsigned short* __restrict__ wg, const float* __restrict__ colsum,
    const float* __restrict__ bd2,
    const unsigned short* __restrict__ wu_b, const float* __restrict__ b_up,
    float* __restrict__ out)
{
    __shared__ float xs[TM * XS];              // raw x, f32: 41088 B
    __shared__ unsigned short g_lds[TM * GP];  // gelu(down), bf16: 1152 B
    __shared__ float s_mean[TM], s_rinv[TM];

    const int tid  = threadIdx.x;
    const int wave = tid >> 6;
    const int lane = tid & 63;
    const int r0   = blockIdx.x * TM;

    // ---- Phase 0: async DMA x -> LDS (f32), zero VGPR cost, deep MLP ----
    // wave w stages rows {2w, 2w+1}, 5 chunks of 1024 B each (lane i -> ldsbase + 16*i)
    {
        #pragma unroll
        for (int rr = 0; rr < 2; ++rr) {
            const int row = wave * 2 + rr;
            const float* gsrc = x + (size_t)(r0 + row) * D_MODEL + lane * 4;
            float* ldst = &xs[row * XS];
            #pragma unroll
            for (int c = 0; c < 5; ++c) {
                __builtin_amdgcn_global_load_lds(
                    (const __attribute__((address_space(1))) unsigned int*)(gsrc + c * 256),
                    (__attribute__((address_space(3))) unsigned int*)(ldst + c * 256),
                    16, 0, 0);
            }
        }
    }
    __syncthreads();   // drains vmcnt + barrier

    // ---- Phase 1: row stats from LDS (32 lanes per row) ----
    {
        const int srow = tid >> 5;      // 0..7
        const int sli  = tid & 31;
        const float* xr = &xs[srow * XS + sli * 4];
        float s = 0.f, sq = 0.f;
        #pragma unroll
        for (int t = 0; t < 10; ++t) {
            float4 v = *reinterpret_cast<const float4*>(xr + t * 128);
            s  += v.x + v.y + v.z + v.w;
            sq += v.x * v.x + v.y * v.y + v.z * v.z + v.w * v.w;
        }
        #pragma unroll
        for (int m = 1; m < 32; m <<= 1) {
            s  += __shfl_xor(s, m);
            sq += __shfl_xor(sq, m);
        }
        const float mean = s * (1.f / D_MODEL);
        const float var  = sq * (1.f / D_MODEL) - mean * mean;
        if (sli == 0) { s_mean[srow] = mean; s_rinv[srow] = rsqrtf(var + LN_EPS); }
    }
    __syncthreads();

    // ---- Phase 2: down-proj on raw x (M=8 via 16x16 MFMA, N=64, K=1280) ----
    const int l15   = lane & 15;
    const int khalf = lane >> 4;        // 0..3
    const int lr    = l15 & 7;          // LDS row (rows 8-15 of MFMA duplicate 0-7)
    const int nn    = wave * 16 + l15;  // bottleneck channel

    floatx4 acc = {0.f, 0.f, 0.f, 0.f};
    {
        const unsigned short* brow = wg + (size_t)nn * D_MODEL + khalf * 8;
        const float* arow = &xs[lr * XS + khalf * 8];
        #pragma unroll 4
        for (int kk = 0; kk < 40; ++kk) {
            float4 a0 = *reinterpret_cast<const float4*>(arow + kk * 32);
            float4 a1 = *reinterpret_cast<const float4*>(arow + kk * 32 + 4);
            short8 b  = *reinterpret_cast<const short8*>(brow + kk * 32);
            acc = __builtin_amdgcn_mfma_f32_16x16x32_bf16(cvt8(a0, a1), b, acc, 0, 0, 0);
        }
    }

    // ---- Phase 3: LN affine + bias + exact GELU -> g_lds ----
    {
        const float cs  = colsum[nn];
        const float bdn = bd2[nn];
        if (khalf < 2) {
            #pragma unroll
            for (int r = 0; r < 4; ++r) {
                const int m = khalf * 4 + r;      // 0..7
                const float yv = s_rinv[m] * (acc[r] - s_mean[m] * cs) + bdn;
                const float gv = 0.5f * yv * (1.f + erff(yv * 0.70710678118654752f));
                g_lds[m * GP + nn] = f2bf(gv);
            }
        }
    }
    __syncthreads();

    // ---- Phase 4: up-proj (M=8, N=1280, K=64) + bias + exact residual ----
    short8 ga0 = *reinterpret_cast<const short8*>(g_lds + lr * GP +  0 + khalf * 8);
    short8 ga1 = *reinterpret_cast<const short8*>(g_lds + lr * GP + 32 + khalf * 8);

    #pragma unroll 2
    for (int i = 0; i < 20; ++i) {
        const int d = (i * 4 + wave) * 16 + l15;
        const unsigned short* bptr = wu_b + (size_t)d * D_BOTTLE + khalf * 8;
        short8 b0 = *reinterpret_cast<const short8*>(bptr);
        short8 b1 = *reinterpret_cast<const short8*>(bptr + 32);
        floatx4 acc2 = {0.f, 0.f, 0.f, 0.f};
        acc2 = __builtin_amdgcn_mfma_f32_16x16x32_bf16(ga0, b0, acc2, 0, 0, 0);
        acc2 = __builtin_amdgcn_mfma_f32_16x16x32_bf16(ga1, b1, acc2, 0, 0, 0);
        const float bu = b_up[d];
        if (khalf < 2) {
            #pragma unroll
            for (int r = 0; r < 4; ++r) {
                const int m = khalf * 4 + r;      // 0..7
                out[(size_t)(r0 + m) * D_MODEL + d] = acc2[r] + bu + xs[m * XS + d];
            }
        }
    }
}

extern "C" void kernel_launch(void* const* d_in, const int* in_sizes, int n_in,
                              void* d_out, int out_size, void* d_ws, size_t ws_size,
                              hipStream_t stream) {
    const float* x      = (const float*)d_in[0];
    const float* gamma  = (const float*)d_in[1];
    const float* beta   = (const float*)d_in[2];
    const float* w_down = (const float*)d_in[3];
    const float* b_down = (const float*)d_in[4];
    const float* w_up   = (const float*)d_in[5];
    const float* b_up   = (const float*)d_in[6];
    float* out = (float*)d_out;

    unsigned short* wg   = (unsigned short*)d_ws;                 // 64*1280 bf16
    unsigned short* wu_b = wg + D_MODEL * D_BOTTLE;               // 1280*64 bf16
    float* colsum = (float*)(wu_b + D_MODEL * D_BOTTLE);          // 64 f32
    float* bd2    = colsum + D_BOTTLE;                            // 64 f32

    prep_weights<<<(D_MODEL * D_BOTTLE + 255) / 256, 256, 0, stream>>>(w_down, gamma, w_up, wg, wu_b);
    prep_reduce<<<D_BOTTLE, 256, 0, stream>>>(wg, w_down, beta, b_down, colsum, bd2);

    const int rows = in_sizes[0] / D_MODEL;   // 24000
    adapter_kernel<<<rows / TM, 256, 0, stream>>>(x, wg, colsum, bd2, wu_b, b_up, out);
}